// Round 3
// baseline (191.402 us; speedup 1.0000x reference)
//
#include <hip/hip_runtime.h>

#define NB   2048
#define SEQ  200
#define DIM  64
#define NH1  64
#define NH2  16
#define EPSF 1e-9f

typedef float fvec4 __attribute__((ext_vector_type(4)));
typedef short svec8 __attribute__((ext_vector_type(8)));   // 8 bf16 = 4 VGPRs

// LDS layout (bytes). Two batches per block.
//   wcb  : Wc B-frags, bf16, frag layout; b0 half [0,8K), b1 half [8K,16K)
//   h1f  : 4 x 2KB per-wave h1 transpose buffers, aliases b0 half (fenced by
//          the second __syncthreads: all wcf reads happen before it)
//   qpart: qterm partials (setup), aliased by outp (epilogue)
#define WCB_OFF    0        // 16384 B
#define QPART_OFF  16384    // 2048 B : qpart / outp alias
#define QALL_OFF   18432    // 512 B  : qterm[2][64]
#define SMEM_BYTES 18944

__device__ __forceinline__ short f2bf(float f) {
    unsigned u = __float_as_uint(f);
    u += 0x7fffu + ((u >> 16) & 1u);      // round-to-nearest-even
    return (short)(u >> 16);
}

__global__ __launch_bounds__(256, 3)
void din_attn_kernel(const float* __restrict__ q,        // [B,64]
                     const float* __restrict__ key,      // [B,200,64]
                     const int*   __restrict__ seqlen,   // [B,1]
                     const float* __restrict__ W1,       // [256,64]
                     const float* __restrict__ alpha1v,
                     const float* __restrict__ mean1v,
                     const float* __restrict__ var1v,
                     const float* __restrict__ W2,       // [64,16]
                     const float* __restrict__ alpha2v,
                     const float* __restrict__ mean2v,
                     const float* __restrict__ var2v,
                     const float* __restrict__ W3,       // [16]
                     float* __restrict__ out)            // [B,64]
{
    __shared__ __align__(16) char smem[SMEM_BYTES];
    char*  wcb   = smem + WCB_OFF;
    char*  h1f   = smem + WCB_OFF;                 // main-loop alias (b0 half)
    float* qpart = (float*)(smem + QPART_OFF);     // [2][4][64]
    float* qall  = (float*)(smem + QALL_OFF);      // [2][64]
    float* outp  = (float*)(smem + QPART_OFF);     // epilogue alias [2][2][64]

    const int b0   = blockIdx.x << 1;              // this block owns b0, b0+1
    const int t    = threadIdx.x;
    const int lane = t & 63;
    const int wave = __builtin_amdgcn_readfirstlane(t >> 6);
    const int qd4  = lane >> 4;     // quad 0..3
    const int m    = lane & 15;
    const int wsub = wave & 1;      // row-phase within my batch
    const int bsel = wave >> 1;     // which batch this wave serves

    const float* q0 = q + (size_t)b0 * DIM;
    const float* q1 = q0 + DIM;

    int ns0 = seqlen[b0];     ns0 = ns0 < SEQ ? ns0 : SEQ;
    int ns1 = seqlen[b0 + 1]; ns1 = ns1 < SEQ ? ns1 : SEQ;
    const int mynseq = bsel ? ns1 : ns0;

    // ---- setup 1: Wc = (W1b - W1c) + q[d]*W1d for BOTH batches from one
    //      W1 read, written as bf16 in frag layout; qterm partials.
    //      Element (d,h) -> frag=(h>>4)*2+(d>>5), slot=((d>>3)&3)*16+(h&15),
    //      byte j=(d&7)*2.
    {
        const int h  = lane;
        const int c  = h >> 4;
        const int mm = h & 15;
        float qt0 = 0.f, qt1 = 0.f;
        #pragma unroll
        for (int i = 0; i < 16; ++i) {
            const int d = wave * 16 + i;
            const float w1a  = W1[(d)       * NH1 + h];
            const float w1b  = W1[(64 + d)  * NH1 + h];
            const float w1c  = W1[(128 + d) * NH1 + h];
            const float w1dd = W1[(192 + d) * NH1 + h];
            const float wbc  = w1b - w1c;
            const float wac  = w1a + w1c;
            const float q0d  = q0[d];              // uniform -> s_load
            const float q1d  = q1[d];
            qt0 = fmaf(q0d, wac, qt0);
            qt1 = fmaf(q1d, wac, qt1);
            const int frag = (c << 1) | (d >> 5);
            const int ln   = (((d >> 3) & 3) << 4) | mm;
            const int off  = (frag << 10) + (ln << 4) + ((d & 7) << 1);
            *(short*)(wcb + off)        = f2bf(fmaf(q0d, w1dd, wbc));
            *(short*)(wcb + 8192 + off) = f2bf(fmaf(q1d, w1dd, wbc));
        }
        qpart[wave * 64 + h]       = qt0;
        qpart[256 + wave * 64 + h] = qt1;
    }
    __syncthreads();

    // ---- setup 2: qterm reduce (both batches); frags to registers; params
    if (t < 128) {
        const int ob = t >> 6, h = t & 63;
        const float* p = qpart + (ob << 8);
        qall[(ob << 6) + h] = (p[h] + p[64 + h]) + (p[128 + h] + p[192 + h]);
    }

    const char* mywcb = wcb + (bsel << 13);
    svec8 wcf[4][2];   // my batch's Wc B-frags (phase-1 B operand)
    #pragma unroll
    for (int c = 0; c < 4; ++c)
        #pragma unroll
        for (int kk = 0; kk < 2; ++kk)
            wcf[c][kk] = *(const svec8*)(mywcb + (((c << 1) | kk) << 10) + (lane << 4));

    // W2 frags, consumed as the A operand of the transposed phase-2:
    // A[row=j=m][k=h=kk*32+qd4*8+jj] = W2[h][j].  Batch-independent.
    svec8 w2f[2];
    #pragma unroll
    for (int kk = 0; kk < 2; ++kk) {
        svec8 f;
        #pragma unroll
        for (int j = 0; j < 8; ++j) {
            const int h = kk * 32 + qd4 * 8 + j;
            f[j] = f2bf(W2[h * NH2 + m]);
        }
        w2f[kk] = f;
    }

    // dice1 params for h = c*16 + m
    float a1p[4], m1p[4], r1p[4];
    #pragma unroll
    for (int c = 0; c < 4; ++c) {
        a1p[c] = alpha1v[c * 16 + m];
        m1p[c] = mean1v[c * 16 + m];
        r1p[c] = rsqrtf(var1v[c * 16 + m] + EPSF);
    }
    // dice2 params for j = qd4*4 + reg (transposed phase-2 output rows)
    float a2p[4], m2p[4], r2p[4], w3p[4];
    #pragma unroll
    for (int reg = 0; reg < 4; ++reg) {
        const int j = qd4 * 4 + reg;
        a2p[reg] = alpha2v[j];
        m2p[reg] = mean2v[j];
        r2p[reg] = rsqrtf(var2v[j] + EPSF);
        w3p[reg] = W3[j];
    }

    __syncthreads();   // wcf reads done -> h1f alias safe; qall ready

    float qtermv[4];
    #pragma unroll
    for (int c = 0; c < 4; ++c) qtermv[c] = qall[(bsel << 6) + c * 16 + m];

    char* myh1 = h1f + (wave << 11);   // 2 KB private transpose buffer
    const float* kb = key + (size_t)(b0 + bsel) * (SEQ * DIM);

    fvec4 oa0 = (fvec4){0.f,0.f,0.f,0.f};   // out cols qd4*8+0..3
    fvec4 oa1 = (fvec4){0.f,0.f,0.f,0.f};   // out cols qd4*8+4..7
    fvec4 oa2 = (fvec4){0.f,0.f,0.f,0.f};   // out cols 32+qd4*8+0..3
    fvec4 oa3 = (fvec4){0.f,0.f,0.f,0.f};   // out cols 32+qd4*8+4..7

    // ---- barrier-free main loop: my wave owns rows wsub*16 + 32k of my
    //      batch; next tile's key loads issue before current tile's compute.
    int rb = wsub << 4;
    if (rb < mynseq) {
        int rm = rb + m;
        rm = rm < SEQ ? rm : SEQ - 1;
        const float* ar = kb + rm * DIM + (qd4 << 3);
        fvec4 f0 = *(const fvec4*)(ar);
        fvec4 f1 = *(const fvec4*)(ar + 4);
        fvec4 f2 = *(const fvec4*)(ar + 32);
        fvec4 f3 = *(const fvec4*)(ar + 36);
        while (true) {
            const int rbn  = rb + 32;
            const bool more = rbn < mynseq;        // wave-uniform
            fvec4 g0, g1, g2, g3;
            if (more) {                            // prefetch next tile
                int rn = rbn + m;
                rn = rn < SEQ ? rn : SEQ - 1;
                const float* br = kb + rn * DIM + (qd4 << 3);
                g0 = *(const fvec4*)(br);
                g1 = *(const fvec4*)(br + 4);
                g2 = *(const fvec4*)(br + 32);
                g3 = *(const fvec4*)(br + 36);
            }

            svec8 a0, a1;
            #pragma unroll
            for (int jj = 0; jj < 4; ++jj) {
                a0[jj]     = f2bf(f0[jj]);
                a0[jj + 4] = f2bf(f1[jj]);
                a1[jj]     = f2bf(f2[jj]);
                a1[jj + 4] = f2bf(f3[jj]);
            }

            // ---- phase 1: x = k @ Wc + qterm (qterm in acc init)
            fvec4 acc[4];
            #pragma unroll
            for (int c = 0; c < 4; ++c) {
                fvec4 a = (fvec4){qtermv[c], qtermv[c], qtermv[c], qtermv[c]};
                a = __builtin_amdgcn_mfma_f32_16x16x32_bf16(a0, wcf[c][0], a, 0, 0, 0);
                a = __builtin_amdgcn_mfma_f32_16x16x32_bf16(a1, wcf[c][1], a, 0, 0, 0);
                acc[c] = a;
            }

            // ---- dice1; h1 -> LDS in frag layout, XOR-swizzled slots
            #pragma unroll
            for (int c = 0; c < 4; ++c) {
                const int kk2 = c >> 1;
                const int qhi = (c & 1) * 2 + (m >> 3);
                #pragma unroll
                for (int reg = 0; reg < 4; ++reg) {
                    const float x  = acc[c][reg];
                    const float xn = (x - m1p[c]) * r1p[c];
                    const float p  = 1.f / (1.f + __expf(-xn));
                    const float h1 = x * (a1p[c] + p * (1.f - a1p[c]));
                    const int l2  = (qhi << 4) | ((qd4 << 2) | reg);
                    const int l2s = l2 ^ ((l2 >> 3) & 7);
                    *(short*)(myh1 + (kk2 << 10) + (l2s << 4) + ((m & 7) << 1))
                        = f2bf(h1);
                }
            }
            // same-wave write->read; compiler inserts lgkmcnt, no barrier

            // ---- phase 2 (operand-swapped): h2^T = W2^T @ h1^T
            //      C[row=j=qd4*4+reg][col=seqrow=m]
            const int slot = lane ^ ((lane >> 3) & 7);
            const svec8 bb0 = *(const svec8*)(myh1 + (slot << 4));
            const svec8 bb1 = *(const svec8*)(myh1 + 1024 + (slot << 4));
            fvec4 acc2 = (fvec4){0.f, 0.f, 0.f, 0.f};
            acc2 = __builtin_amdgcn_mfma_f32_16x16x32_bf16(w2f[0], bb0, acc2, 0, 0, 0);
            acc2 = __builtin_amdgcn_mfma_f32_16x16x32_bf16(w2f[1], bb1, acc2, 0, 0, 0);

            // ---- dice2 + W3: in-lane partial over 4 j's, 2 shfl_xor over
            //      qd4 groups -> each lane holds s for its own row rb+m
            float s = 0.f;
            #pragma unroll
            for (int reg = 0; reg < 4; ++reg) {
                const float x  = acc2[reg];
                const float xn = (x - m2p[reg]) * r2p[reg];
                const float p  = 1.f / (1.f + __expf(-xn));
                const float hd = x * (a2p[reg] + p * (1.f - a2p[reg]));
                s = fmaf(hd, w3p[reg], s);
            }
            s += __shfl_xor(s, 16);
            s += __shfl_xor(s, 32);
            const float w = (rb + m < mynseq) ? 1.f / (1.f + __expf(-s)) : 0.f;

            // ---- phase 3: accumulate w * k-row from registers we hold
            #pragma unroll
            for (int jj = 0; jj < 4; ++jj) {
                oa0[jj] = fmaf(w, f0[jj], oa0[jj]);
                oa1[jj] = fmaf(w, f1[jj], oa1[jj]);
                oa2[jj] = fmaf(w, f2[jj], oa2[jj]);
                oa3[jj] = fmaf(w, f3[jj], oa3[jj]);
            }

            if (!more) break;
            f0 = g0; f1 = g1; f2 = g2; f3 = g3;
            rb = rbn;
        }
    }

    // ---- once-per-kernel reduce over the 16 m-lanes of each q-group
    #pragma unroll
    for (int step = 1; step < 16; step <<= 1) {
        #pragma unroll
        for (int jj = 0; jj < 4; ++jj) {
            oa0[jj] += __shfl_xor(oa0[jj], step);
            oa1[jj] += __shfl_xor(oa1[jj], step);
            oa2[jj] += __shfl_xor(oa2[jj], step);
            oa3[jj] += __shfl_xor(oa3[jj], step);
        }
    }
    if (m == 0) {
        float* op = outp + (bsel << 7) + (wsub << 6) + (qd4 << 3);
        *(fvec4*)(op)          = oa0;
        *(fvec4*)(op + 4)      = oa1;
        *(fvec4*)(op + 32)     = oa2;
        *(fvec4*)(op + 36)     = oa3;
    }
    __syncthreads();
    if (t < 128) {
        const int ob = t >> 6, d = t & 63;
        const float* p = outp + (ob << 7);
        out[(size_t)(b0 + ob) * DIM + d] = p[d] + p[64 + d];
    }
}

extern "C" void kernel_launch(void* const* d_in, const int* in_sizes, int n_in,
                              void* d_out, int out_size, void* d_ws, size_t ws_size,
                              hipStream_t stream) {
    const float* q      = (const float*)d_in[0];
    const float* key    = (const float*)d_in[1];
    const int*   seqlen = (const int*)d_in[2];
    const float* W1     = (const float*)d_in[3];
    const float* alpha1 = (const float*)d_in[4];
    const float* mean1  = (const float*)d_in[5];
    const float* var1   = (const float*)d_in[6];
    const float* W2     = (const float*)d_in[7];
    const float* alpha2 = (const float*)d_in[8];
    const float* mean2  = (const float*)d_in[9];
    const float* var2   = (const float*)d_in[10];
    const float* W3     = (const float*)d_in[11];
    float* out          = (float*)d_out;

    din_attn_kernel<<<NB / 2, 256, 0, stream>>>(q, key, seqlen, W1,
                                                alpha1, mean1, var1,
                                                W2, alpha2, mean2, var2,
                                                W3, out);
}